// Round 1
// baseline (296.306 us; speedup 1.0000x reference)
//
#include <hip/hip_runtime.h>

// Problem: S=8192, D=4096.
// out[s,:] = mask[s] ? source[C(s),:] : inputs[s,:], C(s) = #masked rows < s.
// (The reference's flat S*D cumsum reduces to this because mask is row-constant:
//  inclusive cumsum at (s,d) = C(s)*D + (d+1) when mask[s], so idx = C(s)*D + d.)

#define S_ROWS 8192
#define D_COLS 4096
#define PREP_THREADS 256
#define ROWS_PER_THREAD (S_ROWS / PREP_THREADS)  // 32

// Single-block kernel: detect mask storage layout, compute exclusive prefix
// count of masked rows, and emit rowsrc[s] = C(s) if masked else -1.
__global__ __launch_bounds__(PREP_THREADS) void prep_kernel(
    const void* __restrict__ mask_raw, int* __restrict__ rowsrc) {
  __shared__ int s_not01, s_notF;
  __shared__ int sums[PREP_THREADS];
  __shared__ int excl[PREP_THREADS];
  const int t = threadIdx.x;
  if (t == 0) { s_not01 = 0; s_notF = 0; }
  __syncthreads();

  // Layout detection over the first S_ROWS bytes (valid in every layout):
  //   int32 layout  -> every 4-byte word is 0 or 1
  //   float32 layout-> every word is 0 or 0x3F800000
  //   byte layout   -> words are random packings of 0/1 bytes (neither)
  const unsigned int* w = (const unsigned int*)mask_raw;
  int not01 = 0, notF = 0;
  for (int i = t; i < S_ROWS / 4; i += PREP_THREADS) {
    const unsigned int v = w[i];
    not01 |= (v > 1u) ? 1 : 0;
    notF  |= (v != 0u && v != 0x3F800000u) ? 1 : 0;
  }
  if (not01) atomicOr(&s_not01, 1);
  if (notF)  atomicOr(&s_notF, 1);
  __syncthreads();
  const int mode = (!s_not01) ? 0 : ((!s_notF) ? 1 : 2);  // 0=i32, 1=f32, 2=u8

  // Each thread decodes 32 contiguous rows, local count, then block scan.
  int vals[ROWS_PER_THREAD];
  const int base = t * ROWS_PER_THREAD;
  int local = 0;
  for (int k = 0; k < ROWS_PER_THREAD; ++k) {
    const int s = base + k;
    int mv;
    if (mode == 0)      mv = (((const int*)mask_raw)[s] != 0);
    else if (mode == 1) mv = (((const float*)mask_raw)[s] != 0.0f);
    else                mv = (((const unsigned char*)mask_raw)[s] != 0);
    vals[k] = mv;
    local += mv;
  }
  sums[t] = local;
  __syncthreads();
  if (t == 0) {  // serial 256-element exclusive scan: trivial cost
    int acc = 0;
    for (int i = 0; i < PREP_THREADS; ++i) { excl[i] = acc; acc += sums[i]; }
  }
  __syncthreads();
  int run = excl[t];
  for (int k = 0; k < ROWS_PER_THREAD; ++k) {
    const int s = base + k;
    rowsrc[s] = vals[k] ? run : -1;
    run += vals[k];
  }
}

// Main kernel: one block per output row; copy the selected 16 KiB row with
// float4 (16 B/lane) coalesced loads/stores. 8192 blocks = 32 blocks/CU.
__global__ __launch_bounds__(256) void gather_kernel(
    const float4* __restrict__ in, const float4* __restrict__ src,
    const int* __restrict__ rowsrc, float4* __restrict__ out) {
  const int s = blockIdx.x;
  const int rs = rowsrc[s];
  const float4* __restrict__ p =
      (rs >= 0) ? (src + (size_t)rs * (D_COLS / 4))
                : (in + (size_t)s * (D_COLS / 4));
  float4* __restrict__ o = out + (size_t)s * (D_COLS / 4);
#pragma unroll 4
  for (int i = threadIdx.x; i < D_COLS / 4; i += 256) {
    o[i] = p[i];
  }
}

extern "C" void kernel_launch(void* const* d_in, const int* in_sizes, int n_in,
                              void* d_out, int out_size, void* d_ws, size_t ws_size,
                              hipStream_t stream) {
  const float* inputs = (const float*)d_in[0];
  const void*  mask   = d_in[1];
  const float* source = (const float*)d_in[2];
  float* out = (float*)d_out;
  int* rowsrc = (int*)d_ws;  // 8192 ints = 32 KiB scratch, rewritten every call

  prep_kernel<<<1, PREP_THREADS, 0, stream>>>(mask, rowsrc);
  gather_kernel<<<S_ROWS, 256, 0, stream>>>(
      (const float4*)inputs, (const float4*)source, rowsrc, (float4*)out);
}